// Round 5
// baseline (293.149 us; speedup 1.0000x reference)
//
#include <hip/hip_runtime.h>
#include <hip/hip_bf16.h>

// ---------- types ----------
typedef __bf16 bf16x8 __attribute__((ext_vector_type(8)));
typedef float  f32x4  __attribute__((ext_vector_type(4)));

#define H_DIM 112
#define W_DIM 112
#define CIN 64
#define CMID 192          // 3*64
#define COUT 128
#define NB 16

// ---------------------------------------------------------------
// async 16B global->LDS DMA. LDS dest must be WAVE-UNIFORM; HW adds lane*16.
// ---------------------------------------------------------------
__device__ __forceinline__ void dma16(const void* g, void* l) {
    __builtin_amdgcn_global_load_lds(
        (const __attribute__((address_space(1))) unsigned*)g,
        (__attribute__((address_space(3))) unsigned*)l, 16, 0, 0);
}

// ---------------------------------------------------------------
// Kernel A: repack weights [co][ci][kh][kw] fp32 -> [khw][co][ci] bf16
// ---------------------------------------------------------------
__global__ __launch_bounds__(256) void repack_w_kernel(
    const float* __restrict__ w, __hip_bfloat16* __restrict__ wr)
{
    int idx = blockIdx.x * 256 + threadIdx.x;
    if (idx < 9 * COUT * CMID) {
        int ci  = idx % CMID;
        int t   = idx / CMID;
        int co  = t % COUT;
        int khw = t / COUT;
        wr[idx] = __float2bfloat16(w[(co * CMID + ci) * 9 + khw]);
    }
}

// ---------------------------------------------------------------
// Kernel B: bilinear shift + powers -> y NHWC bf16  [16][112][112][192]
// ---------------------------------------------------------------
__global__ __launch_bounds__(256) void shift_pow_kernel(
    const float* __restrict__ x, const float* __restrict__ shifts,
    __hip_bfloat16* __restrict__ y)
{
    __shared__ __align__(16) float xs[64 * 116];               // 29,696 B
    __shared__ __align__(16) __hip_bfloat16 tile[112 * 104];   // 23,296 B
    __shared__ float4 prm[32];

    const int tid = threadIdx.x;
    const int h   = blockIdx.x;
    const int cb  = blockIdx.y * 32;
    const int n   = blockIdx.z;

    if (tid < 32) {
        float sx = shifts[2 * (cb + tid)]     * 4.0f;
        float sy = shifts[2 * (cb + tid) + 1] * 4.0f;
        float fx = floorf(sx), fy = floorf(sy);
        prm[tid] = make_float4(fx, fy, sx - fx, sy - fy);
    }
    __syncthreads();

    // ---- stage 64 tap-rows (32 ch x 2 taps) of 112 floats each ----
    #pragma unroll
    for (int k = 0; k < 7; ++k) {
        int i     = k * 256 + tid;          // 0..1791
        int rowid = i / 28;                 // 0..63
        int part  = i - rowid * 28;         // 0..27 (float4 chunks)
        int c = rowid >> 1, t = rowid & 1;
        int iy = (int)prm[c].y;
        int r  = h + iy + t;
        bool valid = (unsigned)r < (unsigned)H_DIM;
        int rr = min(max(r, 0), H_DIM - 1);
        float4 v = ((const float4*)(
            x + ((size_t)(n * CIN + cb + c) * H_DIM + rr) * W_DIM))[part];
        if (!valid) v = make_float4(0.f, 0.f, 0.f, 0.f);
        *(float4*)&xs[rowid * 116 + part * 4] = v;
    }
    __syncthreads();

    // ---- compute 32 ch x 112 px ----
    #pragma unroll
    for (int k = 0; k < 14; ++k) {
        int i  = k * 256 + tid;             // 0..3583
        int c  = i / 112;
        int px = i - c * 112;
        float4 p = prm[c];
        int ix = (int)p.x;
        float wx = p.z, wy = p.w;
        int q0 = px + ix, q1 = q0 + 1;
        float f0 = ((unsigned)q0 < (unsigned)W_DIM) ? 1.f : 0.f;
        float f1 = ((unsigned)q1 < (unsigned)W_DIM) ? 1.f : 0.f;
        int a0 = min(max(q0, 0), W_DIM - 1);
        int a1 = min(max(q1, 0), W_DIM - 1);
        const float* r0 = &xs[(2 * c) * 116];
        const float* r1 = &xs[(2 * c + 1) * 116];
        float top = (1.f - wx) * f0 * r0[a0] + wx * f1 * r0[a1];
        float bot = (1.f - wx) * f0 * r1[a0] + wx * f1 * r1[a1];
        float v  = (1.f - wy) * top + wy * bot;
        float v2 = v * v, v3 = v2 * v;
        __hip_bfloat16* tp = &tile[px * 104];
        tp[c]      = __float2bfloat16(v);
        tp[c + 32] = __float2bfloat16(v2);
        tp[c + 64] = __float2bfloat16(v3);
    }
    __syncthreads();

    // ---- write out: 112 px x 12 float4 (96 ch bf16) ----
    const float4* tl4 = (const float4*)tile;   // 13 f4 per px slot
    float4* yo4 = (float4*)(y + ((size_t)(n * H_DIM + h) * W_DIM) * CMID); // 24 f4/px
    const int cbd4 = cb >> 3;                  // 0 or 4 (float4 units)
    #pragma unroll
    for (int k = 0; k < 6; ++k) {
        int i = k * 256 + tid;                 // 0..1535 (1344 valid)
        if (i < 1344) {
            int px  = i / 12;
            int cp4 = i - px * 12;             // 0..11
            int chunk = cp4 >> 2, e4 = cp4 & 3;
            yo4[px * 24 + chunk * 8 + cbd4 + e4] = tl4[px * 13 + cp4];
        }
    }
}

// ---------------------------------------------------------------
// Kernel C: implicit-GEMM 3x3 conv, bf16 MFMA 16x16x32.
//
// ROUND-5 CHANGE (LDS-port redundancy): per (c3) chunk the old code read
// 3 kw-shifted copies of the same 18 slots (63 ds_read_b128/step/wave;
// LDS port = 8.1K cyc/CU-slot vs 1.2K MFMA -> the binding resource at
// 53% util). Now only the kw=1 fragments are read from LDS (21/step);
// kw=0 and kw=2 fragments are derived IN-REGISTER via DPP row-shift
// (+-1 lane within 16-lane rows == the B-operand px/col dimension),
// patching the single edge lane (m=0 / m=15) per row with a 4-lane
// masked ds_read_b128. Row-shl/shr lane-direction convention is
// ambiguous across docs, so direction is SELF-DETECTED at runtime and
// chosen with a uniform cndmask (correct either way).
// Phases per c3, SGB-pinned: P1 {derive e0 || 14 MFMA kw1},
// P2 {derive e2 || 14 MFMA kw0}, P3 {read next bF1 || 14 MFMA kw2}.
// Round-4's vmcnt ordering kept: af loads before the DMA batch.
// ---------------------------------------------------------------
#define YSTR_E 104                  // elements per px slot (208 B)
#define BUF_E  12288                // 24,576 B per buffer (covers DMA overrun)

// shift fragment by one lane within each 16-lane row; both directions
// computed, selected by uniform bool (pick101 -> ctrl 0x101, else 0x111).
__device__ __forceinline__ bf16x8 dpp_sel(bf16x8 v, bool pick101) {
    union { bf16x8 f; int i[4]; } a, r;
    a.f = v;
    #pragma unroll
    for (int d = 0; d < 4; ++d) {
        int x = __builtin_amdgcn_update_dpp(a.i[d], a.i[d], 0x101, 0xF, 0xF, false);
        int y = __builtin_amdgcn_update_dpp(a.i[d], a.i[d], 0x111, 0xF, 0xF, false);
        r.i[d] = pick101 ? x : y;
    }
    return r.f;
}

// one c3 chunk: bF1 holds kw=1 fragments (slots nt*16+m+1, chans C3*32+quad*8)
#define CONV_C3(C3, BF1, BF1N, READ_NEXT) do {                                \
    bf16x8 e0[7], e2[7];                                                      \
    /* P1: kw=1 MFMAs on BF1 ; derive+patch e0 (kw=0, needs src[m-1]) */      \
    _Pragma("unroll")                                                         \
    for (int nt = 0; nt < 7; ++nt) {                                          \
        e0[nt] = dpp_sel(BF1[nt], dn101);                                     \
        if (m == 0)                                                           \
            e0[nt] = *(const bf16x8*)(lbase + (nt * 16) * YSTR_E + (C3) * 32);\
        acc[0][nt] = __builtin_amdgcn_mfma_f32_16x16x32_bf16(                 \
            af[C3][1][0], BF1[nt], acc[0][nt], 0, 0, 0);                      \
        acc[1][nt] = __builtin_amdgcn_mfma_f32_16x16x32_bf16(                 \
            af[C3][1][1], BF1[nt], acc[1][nt], 0, 0, 0);                      \
    }                                                                         \
    _Pragma("unroll")                                                         \
    for (int k_ = 0; k_ < 7; ++k_) {                                          \
        __builtin_amdgcn_sched_group_barrier(0x002, 12, 0); /* VALU  */       \
        __builtin_amdgcn_sched_group_barrier(0x100, 1, 0);  /* DS_RD */       \
        __builtin_amdgcn_sched_group_barrier(0x008, 2, 0);  /* MFMA  */       \
    }                                                                         \
    /* P2: kw=0 MFMAs on e0 ; derive+patch e2 (kw=2, needs src[m+1]) */       \
    _Pragma("unroll")                                                         \
    for (int nt = 0; nt < 7; ++nt) {                                          \
        e2[nt] = dpp_sel(BF1[nt], up101);                                     \
        if (m == 15)                                                          \
            e2[nt] = *(const bf16x8*)(lbase +                                 \
                (nt * 16 + 2) * YSTR_E + (C3) * 32);                          \
        acc[0][nt] = __builtin_amdgcn_mfma_f32_16x16x32_bf16(                 \
            af[C3][0][0], e0[nt], acc[0][nt], 0, 0, 0);                       \
        acc[1][nt] = __builtin_amdgcn_mfma_f32_16x16x32_bf16(                 \
            af[C3][0][1], e0[nt], acc[1][nt], 0, 0, 0);                       \
    }                                                                         \
    _Pragma("unroll")                                                         \
    for (int k_ = 0; k_ < 7; ++k_) {                                          \
        __builtin_amdgcn_sched_group_barrier(0x002, 12, 0);                   \
        __builtin_amdgcn_sched_group_barrier(0x100, 1, 0);                    \
        __builtin_amdgcn_sched_group_barrier(0x008, 2, 0);                    \
    }                                                                         \
    /* P3: kw=2 MFMAs on e2 ; read next c3's kw=1 fragments */                \
    _Pragma("unroll")                                                         \
    for (int nt = 0; nt < 7; ++nt) {                                          \
        if (READ_NEXT)                                                        \
            BF1N[nt] = *(const bf16x8*)(lbase +                               \
                (nt * 16 + 1) * YSTR_E + ((C3) + 1) * 32);                    \
        acc[0][nt] = __builtin_amdgcn_mfma_f32_16x16x32_bf16(                 \
            af[C3][2][0], e2[nt], acc[0][nt], 0, 0, 0);                       \
        acc[1][nt] = __builtin_amdgcn_mfma_f32_16x16x32_bf16(                 \
            af[C3][2][1], e2[nt], acc[1][nt], 0, 0, 0);                       \
    }                                                                         \
    if (READ_NEXT) {                                                          \
        _Pragma("unroll")                                                     \
        for (int k_ = 0; k_ < 7; ++k_) {                                      \
            __builtin_amdgcn_sched_group_barrier(0x100, 1, 0);                \
            __builtin_amdgcn_sched_group_barrier(0x008, 2, 0);                \
        }                                                                     \
    } else {                                                                  \
        __builtin_amdgcn_sched_group_barrier(0x008, 14, 0);                   \
    }                                                                         \
} while (0)

__global__ __launch_bounds__(256, 2) void conv_kernel(
    const __bf16* __restrict__ y,    // [16][112][112][192]
    const __bf16* __restrict__ wr,   // [9][128][192]
    const float* __restrict__ bias,
    float* __restrict__ out)         // [16][128][112][112]
{
    __shared__ __align__(16) __bf16 ybuf[2][BUF_E];   // 49,152 B

    const int tid  = threadIdx.x;
    const int lane = tid & 63;
    const int wid  = tid >> 6;
    const int m    = lane & 15;
    const int quad = lane >> 4;

    // runtime DPP direction probe: is ctrl 0x101 src[m+1] or src[m-1]?
    const int probe = __builtin_amdgcn_update_dpp(0, (int)lane, 0x101, 0xF, 0xF, true);
    const bool up101 = (__builtin_amdgcn_readfirstlane(probe) == 1);
    const bool dn101 = !up101;

    // XCD-chunked swizzle: grid 1792 = 8 XCDs x 224; consecutive ids within
    // a chunk are consecutive h (same n) -> y-row reuse stays in one L2.
    const int bid = blockIdx.x;
    const int id  = (bid & 7) * 224 + (bid >> 3);
    const int n   = id / H_DIM;
    const int h   = id - n * H_DIM;

    // zero halo slots (slot 0 = px -1, slot 113 = px 112) of both buffers
    if (tid < 208) {
        int b    = tid >= 104;
        int r    = tid - b * 104;
        int slot = (r >= 52) ? 113 : 0;
        int dw   = (r >= 52) ? r - 52 : r;
        ((unsigned*)&ybuf[b][0])[slot * 52 + dw] = 0u;
    }

    // per-lane DMA source-offset table: chunk t = 4*j + wid, LDS byte
    // o = 208 + 1024*t + 16*lane -> slot = o/208, rem = o%208.
    int dj[6];
    #pragma unroll
    for (int j = 0; j < 6; ++j) {
        int t = 4 * j + wid;
        int o = 208 + 1024 * t + 16 * lane;
        int slot = o / 208;
        int rem  = o - slot * 208;
        dj[j] = (t < 23 && rem < 192 && slot <= 112)
                    ? ((slot - 1) * 384 + rem) : -1;
    }

    f32x4 acc[2][7];
    #pragma unroll
    for (int mt = 0; mt < 2; ++mt)
        #pragma unroll
        for (int nt = 0; nt < 7; ++nt)
            #pragma unroll
            for (int r = 0; r < 4; ++r) acc[mt][nt][r] = 0.0f;

    const char* ybase = (const char*)y + (size_t)n * (H_DIM * W_DIM * CMID * 2);

    // step s: kh = s>>1 (row h+kh-1), half = s&1 (channels half*96 ..)
    const int f = (h == 0)         ? 2 : 0;
    const int l = (h == H_DIM - 1) ? 3 : 5;

    // ---- stage step f into buffer 0 ----
    {
        int row = h + (f >> 1) - 1, half = f & 1;
        const char* src = ybase + (size_t)row * (W_DIM * CMID * 2) + half * 192;
        char* lb = (char*)&ybuf[0][0];
        #pragma unroll
        for (int j = 0; j < 6; ++j) {
            int t = 4 * j + wid;
            if (dj[j] >= 0) dma16(src + dj[j], lb + 208 + 1024 * t);
        }
    }
    __syncthreads();   // drains first stage

    int buf = 0;
    for (int s = f; s <= l; ++s) {
        const int kh = s >> 1, half = s & 1;

        // ---- (1) af weight loads FIRST (oldest vmcnt entries) ----
        // per-lane K slice = half*96 + c3*32 + quad*8
        bf16x8 af[3][3][2];
        #pragma unroll
        for (int c3 = 0; c3 < 3; ++c3)
            #pragma unroll
            for (int kw = 0; kw < 3; ++kw)
                #pragma unroll
                for (int mt = 0; mt < 2; ++mt)
                    af[c3][kw][mt] = *(const bf16x8*)(
                        wr + (size_t)((kh * 3 + kw) * COUT + wid * 32 + mt * 16 + m) * CMID
                           + half * 96 + c3 * 32 + quad * 8);

        // pin: DMAs below must NOT hoist above the af loads (no-alias would
        // otherwise allow the scheduler to undo the vmcnt ordering)
        __builtin_amdgcn_sched_barrier(0);

        // ---- (2) issue async stage of step s+1 into the other buffer ----
        if (s < l) {
            int row = h + ((s + 1) >> 1) - 1, halfn = (s + 1) & 1;
            const char* src = ybase + (size_t)row * (W_DIM * CMID * 2) + halfn * 192;
            char* lb = (char*)&ybuf[buf ^ 1][0];
            #pragma unroll
            for (int j = 0; j < 6; ++j) {
                int t = 4 * j + wid;
                if (dj[j] >= 0) dma16(src + dj[j], lb + 208 + 1024 * t);
            }
        }

        // ---- (3) compute step s from ybuf[buf] ----
        const __bf16* lbase = &ybuf[buf][m * YSTR_E + quad * 8];

        // prologue: kw=1 fragments of c3=0
        bf16x8 bC[7], bD[7];
        #pragma unroll
        for (int nt = 0; nt < 7; ++nt)
            bC[nt] = *(const bf16x8*)(lbase + (nt * 16 + 1) * YSTR_E + 0 * 32);
        __builtin_amdgcn_sched_group_barrier(0x100, 7, 0);   // 7x DS_READ

        CONV_C3(0, bC, bD, 1);
        CONV_C3(1, bD, bC, 1);
        CONV_C3(2, bC, bD, 0);

        __syncthreads();   // drains stage(s+1) DMA + protects buffer reuse
        buf ^= 1;
    }

    // epilogue: D col = px (lane&15), row = quad*4+r -> co
    #pragma unroll
    for (int mt = 0; mt < 2; ++mt) {
        const int co0 = wid * 32 + mt * 16 + quad * 4;
        float bv[4];
        #pragma unroll
        for (int rr = 0; rr < 4; ++rr) bv[rr] = bias[co0 + rr];
        #pragma unroll
        for (int nt = 0; nt < 7; ++nt) {
            int j = nt * 16 + m;
            #pragma unroll
            for (int rr = 0; rr < 4; ++rr) {
                out[(((size_t)n * COUT + co0 + rr) * H_DIM + h) * W_DIM + j] =
                    acc[mt][nt][rr] + bv[rr];
            }
        }
    }
}

// ---------------------------------------------------------------
extern "C" void kernel_launch(void* const* d_in, const int* in_sizes, int n_in,
                              void* d_out, int out_size, void* d_ws, size_t ws_size,
                              hipStream_t stream) {
    const float* x      = (const float*)d_in[0];
    const float* w      = (const float*)d_in[1];
    const float* bias   = (const float*)d_in[2];
    const float* shifts = (const float*)d_in[3];
    float* out = (float*)d_out;

    __hip_bfloat16* y  = (__hip_bfloat16*)d_ws;                       // 77,070,336 B
    __hip_bfloat16* wr = (__hip_bfloat16*)((char*)d_ws + 77070336);   //    442,368 B

    repack_w_kernel<<<dim3((9 * COUT * CMID + 255) / 256), 256, 0, stream>>>(w, wr);
    shift_pow_kernel<<<dim3(H_DIM, 2, NB), 256, 0, stream>>>(x, shifts, y);
    conv_kernel<<<dim3(H_DIM * NB), 256, 0, stream>>>(
        (const __bf16*)y, (const __bf16*)wr, bias, out);
}